// Round 6
// baseline (287.131 us; speedup 1.0000x reference)
//
#include <hip/hip_runtime.h>
#include <stdint.h>

// RBF kernel matrix: out[i,j] = exp(-gamma * max(||x_i||^2 + ||y_j||^2 - 2 x_i.y_j, 0))
// N=M=8192, D=256, fp32 in/out.
//
// R6: MX-scaled fp8 MFMA (mfma_scale_f32_16x16x128_f8f6f4, unit e8m0 scales
// = plain fp8 at 2x the non-scaled rate, m148) + BK=128 (K-loop = 2 iters,
// 4 barriers/tile vs R5's 8). LDS swizzle sigma(r,s) = r*8 + (s^(r&7)) in
// 16B units: staging 8-lane groups still cover one 128 B global run
// (coalesced), fragment b128 reads hit 8 distinct bank-quads per 8-lane
// burst (conflict-free; R5's pattern was 4-way). Epilogue stores are
// non-temporal (output is never re-read).

typedef __attribute__((ext_vector_type(4))) float f32x4;
typedef __attribute__((ext_vector_type(8))) int   i32x8;

#define NN 8192
#define MM 8192
#define DD 256   // elements per row; fp8 row = 256 bytes
#define BK 128

// ---------------------------------------------------------------------------
// Prep: per-row squared norm (fp32) + fp8-e4m3 conversion of x and y.
// One wave per row: 64 lanes x float4 = 256 elements -> 4 fp8 bytes/lane.
// ---------------------------------------------------------------------------
__global__ __launch_bounds__(256) void prep_kernel(
    const float* __restrict__ x, const float* __restrict__ y,
    unsigned char* __restrict__ xb, unsigned char* __restrict__ yb,
    float* __restrict__ xsq, float* __restrict__ ysq) {
  const int lane = threadIdx.x & 63;
  const int row  = blockIdx.x * 4 + (threadIdx.x >> 6);  // 4 waves/block

  const float* src = x;
  unsigned char* dst = xb;
  float* sq = xsq;
  int r = row;
  if (row >= NN) { src = y; dst = yb; sq = ysq; r = row - NN; }

  const float4 v = reinterpret_cast<const float4*>(src + (size_t)r * DD)[lane];
  float s = v.x * v.x + v.y * v.y + v.z * v.z + v.w * v.w;

  int w = 0;
  w = __builtin_amdgcn_cvt_pk_fp8_f32(v.x, v.y, w, false);  // bytes 0,1
  w = __builtin_amdgcn_cvt_pk_fp8_f32(v.z, v.w, w, true);   // bytes 2,3
  reinterpret_cast<int*>(dst + (size_t)r * DD)[lane] = w;

  #pragma unroll
  for (int o = 32; o > 0; o >>= 1) s += __shfl_down(s, o);
  if (lane == 0) sq[r] = s;
}

// ---------------------------------------------------------------------------
// GEMM + fused RBF epilogue. 128x128 tile / block, 4 waves in 2x2; each wave
// 64x64 via 4x4 grid of 16x16x128 MX-fp8 MFMA tiles, 2 K-iters (BK=128).
//
// LDS chunk c (2 KiB) = rows [c*16,c*16+16) x K-window [kk,kk+128) fp8.
// Slot u (16 B units, 0..127) = r*8 + (s ^ (r&7)): seg s of row r.
// ---------------------------------------------------------------------------
__global__ __launch_bounds__(256, 2) void rbf_gemm_kernel(
    const unsigned char* __restrict__ xb, const unsigned char* __restrict__ yb,
    const float* __restrict__ xsq, const float* __restrict__ ysq,
    const float* __restrict__ gamma, float* __restrict__ out) {
  __shared__ unsigned char As[128 * BK];  // 16 KB, 8 chunks of 2 KiB
  __shared__ unsigned char Bs[128 * BK];  // 16 KB

  const int tid   = threadIdx.x;
  const int lane  = tid & 63;
  const int wave  = tid >> 6;
  const int waveM = wave >> 1;  // 2x2 wave grid
  const int waveN = wave & 1;
  const int row0  = blockIdx.y * 128;
  const int col0  = blockIdx.x * 128;

  f32x4 acc[4][4] = {};

  // Staging: issue p of chunk c covers slots [p*64, p*64+64); lane handles
  // slot p*64+lane -> row r = p*8 + (lane>>3), global seg s = (lane&7)^(lane>>3).
  const int srow = lane >> 3;                      // row within 8-row half
  const int sseg = ((lane & 7) ^ (lane >> 3)) * 16;  // global byte offset

  // Fragment geometry: fm = lane&15 (row), g = lane>>4 (32 B k-window).
  // k-bytes [g*32, g*32+16) at slot (2g)^(fm&7); [g*32+16, +32) at (2g+1)^(fm&7).
  const int fm = lane & 15;
  const int g  = lane >> 4;
  const int off_lo = fm * 128 + (((2 * g)     ^ (fm & 7)) * 16);
  const int off_hi = fm * 128 + (((2 * g + 1) ^ (fm & 7)) * 16);

  #pragma unroll
  for (int kt = 0; kt < 2; ++kt) {
    const int kk = kt * BK;
    __syncthreads();  // previous iteration's ds_reads done before overwrite
    #pragma unroll
    for (int q = 0; q < 2; ++q) {
      const int c = wave * 2 + q;  // wave-uniform chunk id, 8 chunks = 128 rows
      #pragma unroll
      for (int p = 0; p < 2; ++p) {
        const unsigned char* ga =
            xb + (size_t)(row0 + c * 16 + p * 8 + srow) * DD + kk + sseg;
        __builtin_amdgcn_global_load_lds(
            (const __attribute__((address_space(1))) void*)ga,
            (__attribute__((address_space(3))) void*)(As + c * 2048 + p * 1024),
            16, 0, 0);
        const unsigned char* gb =
            yb + (size_t)(col0 + c * 16 + p * 8 + srow) * DD + kk + sseg;
        __builtin_amdgcn_global_load_lds(
            (const __attribute__((address_space(1))) void*)gb,
            (__attribute__((address_space(3))) void*)(Bs + c * 2048 + p * 1024),
            16, 0, 0);
      }
    }
    __syncthreads();  // staging complete

    i32x8 a[4], b[4];
    #pragma unroll
    for (int i = 0; i < 4; ++i) {
      const unsigned char* base = As + (waveM * 4 + i) * 2048;
      const int4 lo = *reinterpret_cast<const int4*>(base + off_lo);
      const int4 hi = *reinterpret_cast<const int4*>(base + off_hi);
      a[i][0] = lo.x; a[i][1] = lo.y; a[i][2] = lo.z; a[i][3] = lo.w;
      a[i][4] = hi.x; a[i][5] = hi.y; a[i][6] = hi.z; a[i][7] = hi.w;
    }
    #pragma unroll
    for (int j = 0; j < 4; ++j) {
      const unsigned char* base = Bs + (waveN * 4 + j) * 2048;
      const int4 lo = *reinterpret_cast<const int4*>(base + off_lo);
      const int4 hi = *reinterpret_cast<const int4*>(base + off_hi);
      b[j][0] = lo.x; b[j][1] = lo.y; b[j][2] = lo.z; b[j][3] = lo.w;
      b[j][4] = hi.x; b[j][5] = hi.y; b[j][6] = hi.z; b[j][7] = hi.w;
    }

    #pragma unroll
    for (int i = 0; i < 4; ++i)
      #pragma unroll
      for (int j = 0; j < 4; ++j)
        acc[i][j] = __builtin_amdgcn_mfma_scale_f32_16x16x128_f8f6f4(
            a[i], b[j], acc[i][j], 0, 0,           // cbsz=fp8, blgp=fp8
            0, 0x7F7F7F7F, 0, 0x7F7F7F7F);        // unit e8m0 scales
  }

  // Epilogue: C/D layout col=lane&15, row=(lane>>4)*4+reg (shape-determined,
  // dtype-independent per m121-128). Non-temporal: output never re-read.
  const float gm = gamma[0];
  const int colb = col0 + waveN * 64 + (lane & 15);
  float ysv[4];
  #pragma unroll
  for (int j = 0; j < 4; ++j) ysv[j] = ysq[colb + j * 16];

  #pragma unroll
  for (int i = 0; i < 4; ++i) {
    #pragma unroll
    for (int r = 0; r < 4; ++r) {
      const int row = row0 + waveM * 64 + i * 16 + (lane >> 4) * 4 + r;
      const float xsv = xsq[row];
      #pragma unroll
      for (int j = 0; j < 4; ++j) {
        float s = xsv + ysv[j] - 2.0f * acc[i][j][r];
        s = fmaxf(s, 0.0f);
        __builtin_nontemporal_store(__expf(-gm * s),
                                    out + (size_t)row * MM + colb + j * 16);
      }
    }
  }
}

// ---------------------------------------------------------------------------
extern "C" void kernel_launch(void* const* d_in, const int* in_sizes, int n_in,
                              void* d_out, int out_size, void* d_ws, size_t ws_size,
                              hipStream_t stream) {
  const float* x     = (const float*)d_in[0];
  const float* y     = (const float*)d_in[1];
  const float* gamma = (const float*)d_in[2];
  float* out = (float*)d_out;

  // Workspace: xb[N*256 B] fp8 | yb[M*256 B] fp8 | xsq[N] f32 | ysq[M] f32
  unsigned char* xb = (unsigned char*)d_ws;
  unsigned char* yb = xb + (size_t)NN * DD;
  float* xsq = (float*)(yb + (size_t)MM * DD);
  float* ysq = xsq + NN;

  prep_kernel<<<(NN + MM) / 4, 256, 0, stream>>>(x, y, xb, yb, xsq, ysq);

  dim3 grid(MM / 128, NN / 128);
  rbf_gemm_kernel<<<grid, 256, 0, stream>>>(xb, yb, xsq, ysq, gamma, out);
}

// Round 7
// 283.988 us; speedup vs baseline: 1.0111x; 1.0111x over previous
//
#include <hip/hip_runtime.h>
#include <stdint.h>

// RBF kernel matrix: out[i,j] = exp(-gamma * max(||x_i||^2 + ||y_j||^2 - 2 x_i.y_j, 0))
// N=M=8192, D=256, fp32 in/out.
//
// R7: A/B role swap. MFMA C/D layout fixes col=lane&15, row=quad*4+reg; with
// A = y-side (output cols) and B = x-side (output rows), each lane holds 4
// CONSECUTIVE OUTPUT COLUMNS of one row -> epilogue becomes 16x
// global_store_dwordx4 per thread (was 64x scalar dword). Same 64 B/row
// wave-level segments, 4x fewer store instructions. Also: NT stores reverted
// (R6 suspect), and pair-preserving XOR swizzle gives 32 B-contiguous
// fragments -> direct i32x8 LDS load (no int4->i32x8 reassembly movs).

typedef __attribute__((ext_vector_type(4))) float f32x4;
typedef __attribute__((ext_vector_type(8))) int   i32x8;

#define NN 8192
#define MM 8192
#define DD 256   // elements per row; fp8 row = 256 bytes
#define BK 128

// ---------------------------------------------------------------------------
// Prep: per-row squared norm (fp32) + fp8-e4m3 conversion of x and y.
// One wave per row: 64 lanes x float4 = 256 elements -> 4 fp8 bytes/lane.
// ---------------------------------------------------------------------------
__global__ __launch_bounds__(256) void prep_kernel(
    const float* __restrict__ x, const float* __restrict__ y,
    unsigned char* __restrict__ xb, unsigned char* __restrict__ yb,
    float* __restrict__ xsq, float* __restrict__ ysq) {
  const int lane = threadIdx.x & 63;
  const int row  = blockIdx.x * 4 + (threadIdx.x >> 6);  // 4 waves/block

  const float* src = x;
  unsigned char* dst = xb;
  float* sq = xsq;
  int r = row;
  if (row >= NN) { src = y; dst = yb; sq = ysq; r = row - NN; }

  const float4 v = reinterpret_cast<const float4*>(src + (size_t)r * DD)[lane];
  float s = v.x * v.x + v.y * v.y + v.z * v.z + v.w * v.w;

  int w = 0;
  w = __builtin_amdgcn_cvt_pk_fp8_f32(v.x, v.y, w, false);  // bytes 0,1
  w = __builtin_amdgcn_cvt_pk_fp8_f32(v.z, v.w, w, true);   // bytes 2,3
  reinterpret_cast<int*>(dst + (size_t)r * DD)[lane] = w;

  #pragma unroll
  for (int o = 32; o > 0; o >>= 1) s += __shfl_down(s, o);
  if (lane == 0) sq[r] = s;
}

// ---------------------------------------------------------------------------
// GEMM + fused RBF epilogue. 128x128 tile / block, 4 waves in 2x2; each wave
// 64x64 via 4x4 grid of 16x16x128 MX-fp8 MFMA tiles, 2 K-iters (BK=128).
// A-side = y rows (output cols), B-side = x rows (output rows).
//
// LDS chunk c (2 KiB) = rows [c*16,c*16+16) x K-window [kk,kk+128) fp8.
// Pair-preserving swizzle: 16 B seg s of row r stored at position
// (s&1) | (((s>>1) ^ (r&3)) << 1)  -> 32 B fragment windows stay contiguous.
// ---------------------------------------------------------------------------
__global__ __launch_bounds__(256, 2) void rbf_gemm_kernel(
    const unsigned char* __restrict__ xb, const unsigned char* __restrict__ yb,
    const float* __restrict__ xsq, const float* __restrict__ ysq,
    const float* __restrict__ gamma, float* __restrict__ out) {
  __shared__ unsigned char As[128 * BK];  // y side (output cols), 16 KB
  __shared__ unsigned char Bs[128 * BK];  // x side (output rows), 16 KB

  const int tid   = threadIdx.x;
  const int lane  = tid & 63;
  const int wave  = tid >> 6;
  const int waveM = wave >> 1;  // y/col side of the 2x2 wave grid
  const int waveN = wave & 1;   // x/row side
  const int row0  = blockIdx.y * 128;  // x rows (output rows)
  const int col0  = blockIdx.x * 128;  // y rows (output cols)

  f32x4 acc[4][4] = {};

  // Staging: issue p of chunk c covers LDS slots [p*64, p*64+64) (16 B each);
  // lane -> row r = p*8 + (lane>>3), slot pos = lane&7, global seg
  // s = (pos&1) | (((pos>>1) ^ (r&3)) << 1). 8-lane groups cover one 128 B
  // global run (segs permuted) -> coalesced.
  const int srow = lane >> 3;
  const int spos = lane & 7;
  const int sseg = ((spos & 1) | (((spos >> 1) ^ (srow & 3)) << 1)) * 16;

  // Fragment: fm = lane&15 (matrix row), g = lane>>4 (32 B k-window).
  // Window g of row fm lives at byte offset fm*128 + (g^(fm&3))*32, 32 B
  // contiguous -> one i32x8 load (2x ds_read_b128, ~2-way banking = free).
  const int fm = lane & 15;
  const int g  = lane >> 4;
  const int foff = fm * 128 + ((g ^ (fm & 3)) * 32);

  #pragma unroll
  for (int kt = 0; kt < 2; ++kt) {
    const int kk = kt * BK;
    __syncthreads();  // previous iteration's ds_reads done before overwrite
    #pragma unroll
    for (int q = 0; q < 2; ++q) {
      const int c = wave * 2 + q;  // wave-uniform chunk id, 8 chunks = 128 rows
      #pragma unroll
      for (int p = 0; p < 2; ++p) {
        const unsigned char* ga =
            yb + (size_t)(col0 + c * 16 + p * 8 + srow) * DD + kk + sseg;
        __builtin_amdgcn_global_load_lds(
            (const __attribute__((address_space(1))) void*)ga,
            (__attribute__((address_space(3))) void*)(As + c * 2048 + p * 1024),
            16, 0, 0);
        const unsigned char* gb =
            xb + (size_t)(row0 + c * 16 + p * 8 + srow) * DD + kk + sseg;
        __builtin_amdgcn_global_load_lds(
            (const __attribute__((address_space(1))) void*)gb,
            (__attribute__((address_space(3))) void*)(Bs + c * 2048 + p * 1024),
            16, 0, 0);
      }
    }
    __syncthreads();  // staging complete

    i32x8 a[4], b[4];
    #pragma unroll
    for (int i = 0; i < 4; ++i)
      a[i] = *reinterpret_cast<const i32x8*>(As + (waveM * 4 + i) * 2048 + foff);
    #pragma unroll
    for (int j = 0; j < 4; ++j)
      b[j] = *reinterpret_cast<const i32x8*>(Bs + (waveN * 4 + j) * 2048 + foff);

    #pragma unroll
    for (int i = 0; i < 4; ++i)
      #pragma unroll
      for (int j = 0; j < 4; ++j)
        acc[i][j] = __builtin_amdgcn_mfma_scale_f32_16x16x128_f8f6f4(
            a[i], b[j], acc[i][j], 0, 0,           // cbsz=fp8, blgp=fp8
            0, 0x7F7F7F7F, 0, 0x7F7F7F7F);        // unit e8m0 scales
  }

  // Epilogue. D[m][n]: m = A row = output col, n = B row = output row.
  // C/D layout: n = lane&15, m = (lane>>4)*4 + reg  ->  each lane holds 4
  // consecutive output cols of one row: float4 stores, full 64 B runs/row.
  const float gm = gamma[0];
  const int rowb = row0 + waveN * 64 + (lane & 15);
  const int colq = col0 + waveM * 64 + (lane >> 4) * 4;

  float xsv[4];
  #pragma unroll
  for (int j = 0; j < 4; ++j) xsv[j] = xsq[rowb + j * 16];
  float4 ysv[4];
  #pragma unroll
  for (int i = 0; i < 4; ++i)
    ysv[i] = *reinterpret_cast<const float4*>(ysq + colq + i * 16);

  #pragma unroll
  for (int j = 0; j < 4; ++j) {
    const size_t obase = (size_t)(rowb + j * 16) * MM;
    #pragma unroll
    for (int i = 0; i < 4; ++i) {
      float4 v;
      float s;
      s = xsv[j] + ysv[i].x - 2.0f * acc[i][j][0]; v.x = __expf(-gm * fmaxf(s, 0.0f));
      s = xsv[j] + ysv[i].y - 2.0f * acc[i][j][1]; v.y = __expf(-gm * fmaxf(s, 0.0f));
      s = xsv[j] + ysv[i].z - 2.0f * acc[i][j][2]; v.z = __expf(-gm * fmaxf(s, 0.0f));
      s = xsv[j] + ysv[i].w - 2.0f * acc[i][j][3]; v.w = __expf(-gm * fmaxf(s, 0.0f));
      *reinterpret_cast<float4*>(out + obase + colq + i * 16) = v;
    }
  }
}

// ---------------------------------------------------------------------------
extern "C" void kernel_launch(void* const* d_in, const int* in_sizes, int n_in,
                              void* d_out, int out_size, void* d_ws, size_t ws_size,
                              hipStream_t stream) {
  const float* x     = (const float*)d_in[0];
  const float* y     = (const float*)d_in[1];
  const float* gamma = (const float*)d_in[2];
  float* out = (float*)d_out;

  // Workspace: xb[N*256 B] fp8 | yb[M*256 B] fp8 | xsq[N] f32 | ysq[M] f32
  unsigned char* xb = (unsigned char*)d_ws;
  unsigned char* yb = xb + (size_t)NN * DD;
  float* xsq = (float*)(yb + (size_t)MM * DD);
  float* ysq = xsq + NN;

  prep_kernel<<<(NN + MM) / 4, 256, 0, stream>>>(x, y, xb, yb, xsq, ysq);

  dim3 grid(MM / 128, NN / 128);
  rbf_gemm_kernel<<<grid, 256, 0, stream>>>(xb, yb, xsq, ysq, gamma, out);
}